// Round 7
// baseline (1915.913 us; speedup 1.0000x reference)
//
#include <hip/hip_runtime.h>

#define BB 64
#define TT 512
#define HH 1024
#define OUTN 32000
#define NDOM 4              // 4 independent domains: 16 batch rows each
#define NCB 32              // col-blocks per domain (32 cols each)
#define NWG (NDOM * NCB)    // 128 workgroups
#define NTH 128             // 2 waves; each wave owns 16 of the WG's 32 cols
#define SLOT (BB * HH * 2)  // 128 KB per ring slot
// ring of 3 slots at d_ws; slot: [dom 0..3][kb 0..31][row 0..15][col 0..31] bf16
// chunk = 16 B = (row, 8 cols) stored by ONE lane's dwordx4 (atomic unit);
// bit14 of chunk's first u16 = step phase (tanh output => bit14 is 0).
// NO flag array: the data IS the flag, verified per 8-block GROUP.

typedef __attribute__((ext_vector_type(8))) short s16x8;
typedef __attribute__((ext_vector_type(4))) float f32x4;
typedef __attribute__((ext_vector_type(4))) int i32x4;

static __device__ __forceinline__ unsigned short f2bf(float f) {
  union { float f; unsigned u; } a; a.f = f;
  unsigned r = a.u + 0x7fffu + ((a.u >> 16) & 1u);   // RNE
  return (unsigned short)(r >> 16);
}

static __device__ __forceinline__ float ftanh(float x) {
  float e = __expf(2.0f * x);
  return 1.0f - 2.0f * __builtin_amdgcn_rcpf(e + 1.0f);
}

// device-scope load (coherent point), static areg index only
#define ALD(idx, off_lit, vov)                                            \
  asm volatile("global_load_dwordx4 %0, %1, %2 offset:" #off_lit " sc1"   \
               : "=v"(areg[idx]) : "v"(vov), "s"(hprev) : "memory")

#define LDG0 { ALD(0,0,vo0);  ALD(1,1024,vo0);  ALD(2,2048,vo0);  ALD(3,3072,vo0);  \
               ALD(4,0,vo1);  ALD(5,1024,vo1);  ALD(6,2048,vo1);  ALD(7,3072,vo1); }
#define LDG1 { ALD(8,0,vo2);  ALD(9,1024,vo2);  ALD(10,2048,vo2); ALD(11,3072,vo2); \
               ALD(12,0,vo3); ALD(13,1024,vo3); ALD(14,2048,vo3); ALD(15,3072,vo3); }
#define LDG2 { ALD(16,0,vo4); ALD(17,1024,vo4); ALD(18,2048,vo4); ALD(19,3072,vo4); \
               ALD(20,0,vo5); ALD(21,1024,vo5); ALD(22,2048,vo5); ALD(23,3072,vo5); }
#define LDG3 { ALD(24,0,vo6); ALD(25,1024,vo6); ALD(26,2048,vo6); ALD(27,3072,vo6); \
               ALD(28,0,vo7); ALD(29,1024,vo7); ALD(30,2048,vo7); ALD(31,3072,vo7); }

// verify group gg: all 64 lanes' chunks carry the wanted phase bit
#define VERG(gg)                                                          \
  if (!((gdone >> gg) & 1)) {                                             \
    unsigned bad = 0;                                                     \
    _Pragma("unroll") for (int j = 0; j < 8; ++j)                         \
        bad |= (((unsigned)areg[gg * 8 + j][0]) ^ want) & 0x4000u;        \
    if (__all(bad == 0)) gdone |= 1u << gg;                               \
  }

// process group gg (in-order prefix only -> deterministic fp32 sum order)
#define PRCG(gg)                                                          \
  if (gnext == gg && ((gdone >> gg) & 1)) {                               \
    _Pragma("unroll") for (int j = 0; j < 8; ++j) {                       \
      areg[gg * 8 + j][0] &= ~0x4000;                                     \
      union { i32x4 i; s16x8 s; } a_; a_.i = areg[gg * 8 + j];            \
      s16x8 b_ = *reinterpret_cast<const s16x8*>(                         \
          &wlds[(((gg * 8 + j) * 2 + wv) * 64 + l) * 8]);                 \
      ac[j & 3] = __builtin_amdgcn_mfma_f32_16x16x32_bf16(                \
          a_.s, b_, ac[j & 3], 0, 0, 0);                                  \
    }                                                                     \
    gnext = gg + 1;                                                       \
  }

__global__ __launch_bounds__(NTH, 1) void rnn_persist(
    const int* __restrict__ x, const float* __restrict__ Wxh,
    const float* __restrict__ Whh_w, const float* __restrict__ Whh_b,
    char* __restrict__ hbuf) {
  const int g = blockIdx.x;
  const int dom = g >> 5;          // batch rows [16*dom, +16)
  const int cb = g & 31;           // cols [32*cb, +32)
  const int tid = threadIdx.x;
  const int wv = tid >> 6;
  const int l = tid & 63;
  const int lr = l & 15;
  const int lq = l >> 4;

  __shared__ __align__(16) unsigned short wlds[32 * 2 * 64 * 8];  // 64 KB B-frags
  __shared__ __align__(16) unsigned short epi[16 * 32];           // 1 KB repack
  // epi cols [0,16) are wave0-private, [16,32) wave1-private -> no barrier.

  // One-time B pack (MFMA B-fragment order)
  for (int e = tid; e < 32 * 2 * 64; e += NTH) {
    int kb = e >> 7;
    int nt = (e >> 6) & 1;
    int ln = e & 63;
    int col = cb * 32 + nt * 16 + (ln & 15);
    int k0 = kb * 32 + (ln >> 4) * 8;
    const float* src = Whh_w + (size_t)col * HH + k0;
    union { unsigned short u[8]; i32x4 v; } pk;
    #pragma unroll
    for (int j = 0; j < 8; ++j) pk.u[j] = f2bf(src[j]);
    *reinterpret_cast<i32x4*>(&wlds[(size_t)e * 8]) = pk.v;
  }
  const int mycol = cb * 32 + wv * 16 + lr;
  const float bias = Whh_b[mycol];
  __syncthreads();   // only barrier in the kernel

  int xrow[4], xv[4];
  #pragma unroll
  for (int i = 0; i < 4; ++i) {
    xrow[i] = (dom * 16 + lq * 4 + i) * TT;
    xv[i] = x[xrow[i]];
  }

  const unsigned vo0 = (unsigned)(lr * 64 + lq * 16);
  const unsigned vo1 = vo0 + 4096, vo2 = vo0 + 8192, vo3 = vo0 + 12288;
  const unsigned vo4 = vo0 + 16384, vo5 = vo0 + 20480, vo6 = vo0 + 24576,
                 vo7 = vo0 + 28672;

  for (int s = 0; s < TT; ++s) {
    const char* hprev = hbuf + (s % 3) * SLOT + dom * 32768;
    char* hcur = hbuf + ((s + 1) % 3) * SLOT + dom * 32768;

    // embedding gather — cached loads, drain under round-1's vmcnt
    float ev[4];
    #pragma unroll
    for (int i = 0; i < 4; ++i) ev[i] = Wxh[(size_t)xv[i] * HH + mycol];

    const unsigned want = ((unsigned)(s & 1)) << 14;
    f32x4 ac[4];
    #pragma unroll
    for (int c = 0; c < 4; ++c) ac[c] = (f32x4){0.f, 0.f, 0.f, 0.f};

    i32x4 areg[32];
    unsigned gdone = 0;
    int gnext = 0;
    int guard = 0;
    while (gnext < 4) {
      // (re)issue loads for unverified groups
      if (!((gdone >> 0) & 1)) LDG0;
      if (!((gdone >> 1) & 1)) LDG1;
      if (!((gdone >> 2) & 1)) LDG2;
      if (!((gdone >> 3) & 1)) LDG3;
      // overlap flight with MFMA of groups verified in earlier rounds
      PRCG(0) PRCG(1) PRCG(2) PRCG(3)
      asm volatile("s_waitcnt vmcnt(0)" ::: "memory");
      __builtin_amdgcn_sched_barrier(0);
      VERG(0) VERG(1) VERG(2) VERG(3)
      PRCG(0) PRCG(1) PRCG(2) PRCG(3)
      if (++guard > (1 << 17)) break;   // safety valve: never hard-wedge
    }
    f32x4 acc = (ac[0] + ac[1]) + (ac[2] + ac[3]);

    // prefetch next step's tokens (L2-hot)
    if (s + 1 < TT) {
      #pragma unroll
      for (int i = 0; i < 4; ++i) xv[i] = x[xrow[i] + s + 1];
    }

    // epilogue (wave-private): C/D col=lane&15, row=(lane>>4)*4+i
    #pragma unroll
    for (int i = 0; i < 4; ++i) {
      float v = ftanh(acc[i] + ev[i] + bias);
      epi[(lq * 4 + i) * 32 + wv * 16 + lr] = f2bf(v);
    }
    asm volatile("s_waitcnt lgkmcnt(0)" ::: "memory");  // wave-local LDS order
    __builtin_amdgcn_sched_barrier(0);
    // each wave stores its own 32 chunks (rows 0..15 x its 2 col-groups)
    if (l < 32) {
      int r = l >> 1, cg = wv * 2 + (l & 1);
      i32x4 v = *reinterpret_cast<const i32x4*>(&epi[r * 32 + cg * 8]);
      v[0] |= (int)(((unsigned)((s + 1) & 1)) << 14);
      char* dst = hcur + cb * 1024 + r * 64 + cg * 16;
      asm volatile("global_store_dwordx4 %0, %1, off sc1"
                   :: "v"(dst), "v"(v) : "memory");
    }
    // no wait: the store drains under next step's round-1 vmcnt
  }
}

// out[64][32000] = h_final @ Why^T + Why_b; h_512 = ring slot 2 (512%3==2),
// phase bit (512&1)==0 -> data is clean, no fixup.
__global__ __launch_bounds__(256) void rnn_proj(
    const char* __restrict__ hfin, const float* __restrict__ Why_w,
    const float* __restrict__ Why_b, float* __restrict__ out) {
  const int tid = threadIdx.x;
  const int w = tid >> 6;
  const int l = tid & 63;
  const int lr = l & 15;
  const int lq = l >> 4;
  const int nbase = blockIdx.x * 128;
  const int row = w * 16 + lr;

  f32x4 acc[8];
  #pragma unroll
  for (int nt = 0; nt < 8; ++nt) acc[nt] = (f32x4){0.f, 0.f, 0.f, 0.f};

  const char* abase = hfin + (size_t)(row >> 4) * 32768 + (row & 15) * 64 + lq * 16;
  for (int kb = 0; kb < 32; ++kb) {
    s16x8 a = *reinterpret_cast<const s16x8*>(abase + kb * 1024);
    #pragma unroll
    for (int nt = 0; nt < 8; ++nt) {
      int n = nbase + nt * 16 + lr;
      const float* wp = Why_w + (size_t)n * HH + kb * 32 + lq * 8;
      union { unsigned short u[8]; s16x8 v; } bb;
      #pragma unroll
      for (int j = 0; j < 8; ++j) bb.u[j] = f2bf(wp[j]);
      acc[nt] = __builtin_amdgcn_mfma_f32_16x16x32_bf16(a, bb.v, acc[nt], 0, 0, 0);
    }
  }
  #pragma unroll
  for (int nt = 0; nt < 8; ++nt) {
    int n = nbase + nt * 16 + lr;
    float bv = Why_b[n];
    #pragma unroll
    for (int i = 0; i < 4; ++i) {
      int b = w * 16 + lq * 4 + i;
      out[(size_t)b * OUTN + n] = acc[nt][i] + bv;
    }
  }
}

extern "C" void kernel_launch(void* const* d_in, const int* in_sizes, int n_in,
                              void* d_out, int out_size, void* d_ws, size_t ws_size,
                              hipStream_t stream) {
  const int* x = (const int*)d_in[0];
  const float* Wxh = (const float*)d_in[1];
  const float* Whh_w = (const float*)d_in[2];
  const float* Whh_b = (const float*)d_in[3];
  const float* Why_w = (const float*)d_in[4];
  const float* Why_b = (const float*)d_in[5];
  float* out = (float*)d_out;

  char* hbuf = (char*)d_ws;   // 3 ring slots x 128 KB

  // slot0 = h_0 = zeros (phase0 valid); slot1 = 0x00 (bit14=0 != phase1);
  // slot2 = 0x40 (bit14=1 != phase0). Re-done every call — deterministic.
  hipMemsetAsync(hbuf, 0x00, 2 * SLOT, stream);
  hipMemsetAsync(hbuf + 2 * SLOT, 0x40, SLOT, stream);
  rnn_persist<<<NWG, NTH, 0, stream>>>(x, Wxh, Whh_w, Whh_b, hbuf);
  rnn_proj<<<OUTN / 128, 256, 0, stream>>>(hbuf + 2 * SLOT, Why_w, Why_b, out);
}